// Round 10
// baseline (166.163 us; speedup 1.0000x reference)
//
#include <hip/hip_runtime.h>

typedef short bf16x8 __attribute__((ext_vector_type(8)));
typedef float f32x4 __attribute__((ext_vector_type(4)));

#define D 128
#define NROW 98304          // 3 groups * 64 mc * 512 rows
#define X_ELEMS ((size_t)NROW * D)          // bf16 elements in ws
#define NBLK 3072                           // dist blocks = partial slots
#define INV_COUNT 5.9604644775390625e-08f   // 1 / (64*512*512)

typedef __attribute__((address_space(3))) void  as3_void;
typedef const __attribute__((address_space(1))) void as1_cvoid;

__device__ __forceinline__ void gl2lds16(const void* g, void* l) {
    __builtin_amdgcn_global_load_lds((as1_cvoid*)g, (as3_void*)l, 16, 0, 0);
}

__device__ __forceinline__ unsigned short f2bf(float f) {
    unsigned u = __float_as_uint(f);
    u += 0x7FFFu + ((u >> 16) & 1u);        // round-to-nearest-even
    return (unsigned short)(u >> 16);
}
__device__ __forceinline__ float bf2f(unsigned short h) {
    return __uint_as_float(((unsigned)h) << 16);
}

// 8 rows per block; 32 threads per row: float4 loads, 8B bf16 store,
// width-32 shuffle reduce for sum(x_bf16^2).
__global__ __launch_bounds__(256) void prep_kernel(
    const float* __restrict__ mu, const float* __restrict__ sigma,
    const float* __restrict__ epsA, const float* __restrict__ epsB,
    const float* __restrict__ epsC,
    unsigned short* __restrict__ Xb, float* __restrict__ sumsq)
{
    int t = threadIdx.x;
    int row  = blockIdx.x * 8 + (t >> 5);   // 0..NROW-1
    int ci   = t & 31;                      // float4 index within row
    int n  = row & 511;
    int gm = row >> 9;        // g*64 + m
    int g  = gm >> 6;
    int m  = gm & 63;
    const float* eps = (g == 0) ? epsA : (g == 1) ? epsB : epsC;
    float4 e = ((const float4*)(eps + ((size_t)m * 512 + n) * D))[ci];
    float4 u = ((const float4*)(mu    + ((size_t)(g * 512 + n)) * D))[ci];
    float4 s = ((const float4*)(sigma + ((size_t)(g * 512 + n)) * D))[ci];
    unsigned short b0 = f2bf(fmaf(s.x, e.x, u.x));
    unsigned short b1 = f2bf(fmaf(s.y, e.y, u.y));
    unsigned short b2 = f2bf(fmaf(s.z, e.z, u.z));
    unsigned short b3 = f2bf(fmaf(s.w, e.w, u.w));
    float f0 = bf2f(b0), f1 = bf2f(b1), f2 = bf2f(b2), f3 = bf2f(b3);
    float ss = f0 * f0 + f1 * f1 + f2 * f2 + f3 * f3;
    uint2 packed;
    packed.x = (unsigned)b0 | ((unsigned)b1 << 16);
    packed.y = (unsigned)b2 | ((unsigned)b3 << 16);
    ((uint2*)(Xb + (size_t)row * D))[ci] = packed;
    #pragma unroll
    for (int o = 16; o > 0; o >>= 1) ss += __shfl_down(ss, o, 32);
    if (ci == 0) sumsq[row] = ss;
}

// One block = one 128x128 tile. K=128 in two stage+compute phases through
// ONE half-K LDS pair = exactly 32 KB -> 5 blocks/CU (was 4 at 33.8 KB).
// Blocks/CU is the proven lever: each +1 resident block adds barrier-drain
// cover (R8->R9: 2->4 blocks = -14.5 us wall). sumsq is read straight from
// L2 in the epilogue (no LDS staging) to keep LDS at the 32 KB boundary.
__global__ __launch_bounds__(256, 5) void dist_kernel(
    const unsigned short* __restrict__ Xb, const float* __restrict__ sumsq,
    float* __restrict__ pslots)
{
    const int bx   = blockIdx.x;          // 0..3071
    const int xcd  = bx & 7;
    const int k    = bx >> 3;             // 0..383
    const int j    = k >> 4;              // 0..23
    const int tile = k & 15;
    const int s    = xcd + 8 * j;         // slice 0..191 = dist*64 + m
    const int dist = s >> 6;
    const int m    = s & 63;
    const int tn   = tile >> 2, tk = tile & 3;

    // dist 0: AC (x=A=0, y=C=2); dist 1: BA (x=B=1, y=A=0); dist 2: BC (x=B=1, y=C=2)
    const int gx = (dist == 0) ? 0 : 1;
    const int gy = (dist == 1) ? 0 : 2;

    const char* Xa = (const char*)(Xb + (((size_t)(gx * 64 + m)) * 512 + tn * 128) * D);
    const char* Xc = (const char*)(Xb + (((size_t)(gy * 64 + m)) * 512 + tk * 128) * D);
    const float* ssx = sumsq + ((size_t)(gx * 64 + m)) * 512 + tn * 128;
    const float* ssy = sumsq + ((size_t)(gy * 64 + m)) * 512 + tk * 128;

    __shared__ unsigned short As[128 * 64];   // 16 KB, half-K A
    __shared__ unsigned short Bs[128 * 64];   // 16 KB, half-K B  (total = 32 KB exactly)

    const int t = threadIdx.x;
    const int wave = t >> 6, lane = t & 63;
    const int wr = (wave >> 1) * 64;      // wave's 64x64 quadrant
    const int wc = (wave & 1) * 64;
    const int l15 = lane & 15, quad = lane >> 4;

    // staging lane map: 8 rows x 8 granules per instr (1 KB).
    // LDS granule-in-row sg = lane&7; global granule g = sg ^ (row&7).
    const int dr8 = lane >> 3, g8 = lane & 7;
    const int voff = dr8 * 256 + ((g8 ^ dr8) * 16);

    f32x4 acc[4][4] = {};

    // ---- phase 0: stage K-cols [0,64) ----
    #pragma unroll
    for (int i = 0; i < 4; i++) {
        const int r0 = wave * 32 + i * 8;
        gl2lds16(Xa + r0 * 256 + voff, &As[r0 * 64]);
        gl2lds16(Xc + r0 * 256 + voff, &Bs[r0 * 64]);
    }
    __syncthreads();

    #pragma unroll
    for (int ks = 0; ks < 2; ks++) {
        const int base = ((ks * 4 + quad) ^ (l15 & 7)) * 8;
        bf16x8 a[4], b[4];
        #pragma unroll
        for (int fr = 0; fr < 4; fr++)
            a[fr] = *(bf16x8*)&As[(wr + fr * 16 + l15) * 64 + base];
        #pragma unroll
        for (int fc = 0; fc < 4; fc++)
            b[fc] = *(bf16x8*)&Bs[(wc + fc * 16 + l15) * 64 + base];
        #pragma unroll
        for (int fr = 0; fr < 4; fr++)
            #pragma unroll
            for (int fc = 0; fc < 4; fc++)
                acc[fr][fc] = __builtin_amdgcn_mfma_f32_16x16x32_bf16(
                    a[fr], b[fc], acc[fr][fc], 0, 0, 0);
    }
    __syncthreads();

    // ---- phase 1: stage K-cols [64,128) into the same buffer ----
    #pragma unroll
    for (int i = 0; i < 4; i++) {
        const int r0 = wave * 32 + i * 8;
        gl2lds16(Xa + r0 * 256 + 128 + voff, &As[r0 * 64]);
        gl2lds16(Xc + r0 * 256 + 128 + voff, &Bs[r0 * 64]);
    }
    __syncthreads();

    #pragma unroll
    for (int ks = 0; ks < 2; ks++) {
        const int base = ((ks * 4 + quad) ^ (l15 & 7)) * 8;
        bf16x8 a[4], b[4];
        #pragma unroll
        for (int fr = 0; fr < 4; fr++)
            a[fr] = *(bf16x8*)&As[(wr + fr * 16 + l15) * 64 + base];
        #pragma unroll
        for (int fc = 0; fc < 4; fc++)
            b[fc] = *(bf16x8*)&Bs[(wc + fc * 16 + l15) * 64 + base];
        #pragma unroll
        for (int fr = 0; fr < 4; fr++)
            #pragma unroll
            for (int fc = 0; fc < 4; fc++)
                acc[fr][fc] = __builtin_amdgcn_mfma_f32_16x16x32_bf16(
                    a[fr], b[fc], acc[fr][fc], 0, 0, 0);
    }

    // ---- epilogue: d2 = x2 + y2 - 2*dot; C layout: col=lane&15, row=quad*4+i
    // sumsq rows read straight from global (L2-hot, 20 dwords/thread).
    float lsum = 0.f;
    #pragma unroll
    for (int fc = 0; fc < 4; fc++) {
        float y2 = ssy[wc + fc * 16 + l15];
        #pragma unroll
        for (int fr = 0; fr < 4; fr++) {
            float x2 = ssx[wr + fr * 16 + quad * 4];     // +i below, same cacheline
            #pragma unroll
            for (int i = 0; i < 4; i++) {
                float x2i = ssx[wr + fr * 16 + quad * 4 + i];
                float d2 = fmaxf(fmaf(-2.f, acc[fr][fc][i], x2i + y2), 1e-12f);
                if (dist == 0) {
                    lsum += d2;                               // mean(dAC^2)
                } else if (d2 < 4.f) {                        // relu(M - d), M=2
                    float td = 2.f - sqrtf(d2);
                    lsum += td * td;
                }
            }
            (void)x2;
        }
    }

    #pragma unroll
    for (int o = 32; o > 0; o >>= 1) lsum += __shfl_down(lsum, o, 64);
    __syncthreads();                      // all LDS reads done; reuse As
    float* red = (float*)As;
    if (lane == 0) red[wave] = lsum;
    __syncthreads();
    if (t == 0)
        pslots[bx] = red[0] + red[1] + red[2] + red[3];   // plain store, no atomic
}

// Final reduction: 1 block, 256 threads, 12 floats each -> out[0].
__global__ __launch_bounds__(256) void reduce_kernel(
    const float* __restrict__ pslots, float* __restrict__ out)
{
    const int t = threadIdx.x;
    float s = 0.f;
    #pragma unroll
    for (int i = 0; i < 3; i++) {
        float4 v = ((const float4*)pslots)[t + i * 256];
        s += v.x + v.y + v.z + v.w;
    }
    #pragma unroll
    for (int o = 32; o > 0; o >>= 1) s += __shfl_down(s, o, 64);
    __shared__ float red[4];
    const int wave = t >> 6, lane = t & 63;
    if (lane == 0) red[wave] = s;
    __syncthreads();
    if (t == 0) out[0] = (red[0] + red[1] + red[2] + red[3]) * INV_COUNT;
}

extern "C" void kernel_launch(void* const* d_in, const int* in_sizes, int n_in,
                              void* d_out, int out_size, void* d_ws, size_t ws_size,
                              hipStream_t stream) {
    const float* mu    = (const float*)d_in[0];
    const float* sigma = (const float*)d_in[1];
    const float* epsA  = (const float*)d_in[2];
    const float* epsB  = (const float*)d_in[3];
    const float* epsC  = (const float*)d_in[4];
    float* out = (float*)d_out;

    unsigned short* Xb = (unsigned short*)d_ws;              // 25.17 MB bf16
    float* sumsq  = (float*)((char*)d_ws + X_ELEMS * sizeof(unsigned short)); // 0.39 MB
    float* pslots = sumsq + NROW;                            // 12 KB partials

    prep_kernel<<<NROW / 8, 256, 0, stream>>>(mu, sigma, epsA, epsB, epsC, Xb, sumsq);

    dist_kernel<<<NBLK, 256, 0, stream>>>(Xb, sumsq, pslots);

    reduce_kernel<<<1, 256, 0, stream>>>(pslots, out);
}

// Round 11
// 118.628 us; speedup vs baseline: 1.4007x; 1.4007x over previous
//
#include <hip/hip_runtime.h>

typedef short bf16x8 __attribute__((ext_vector_type(8)));
typedef float f32x4 __attribute__((ext_vector_type(4)));

#define D 128
#define NROW 98304          // 3 groups * 64 mc * 512 rows
#define X_ELEMS ((size_t)NROW * D)          // bf16 elements in ws
#define NBLK 3072                           // dist blocks = partial slots
#define INV_COUNT 5.9604644775390625e-08f   // 1 / (64*512*512)

typedef __attribute__((address_space(3))) void  as3_void;
typedef const __attribute__((address_space(1))) void as1_cvoid;

__device__ __forceinline__ void gl2lds16(const void* g, void* l) {
    __builtin_amdgcn_global_load_lds((as1_cvoid*)g, (as3_void*)l, 16, 0, 0);
}
__device__ __forceinline__ void gl2lds4(const void* g, void* l) {
    __builtin_amdgcn_global_load_lds((as1_cvoid*)g, (as3_void*)l, 4, 0, 0);
}

__device__ __forceinline__ unsigned short f2bf(float f) {
    unsigned u = __float_as_uint(f);
    u += 0x7FFFu + ((u >> 16) & 1u);        // round-to-nearest-even
    return (unsigned short)(u >> 16);
}
__device__ __forceinline__ float bf2f(unsigned short h) {
    return __uint_as_float(((unsigned)h) << 16);
}

// 8 rows per block; 32 threads per row: float4 loads, 8B bf16 store,
// width-32 shuffle reduce for sum(x_bf16^2).
__global__ __launch_bounds__(256) void prep_kernel(
    const float* __restrict__ mu, const float* __restrict__ sigma,
    const float* __restrict__ epsA, const float* __restrict__ epsB,
    const float* __restrict__ epsC,
    unsigned short* __restrict__ Xb, float* __restrict__ sumsq)
{
    int t = threadIdx.x;
    int row  = blockIdx.x * 8 + (t >> 5);   // 0..NROW-1
    int ci   = t & 31;                      // float4 index within row
    int n  = row & 511;
    int gm = row >> 9;        // g*64 + m
    int g  = gm >> 6;
    int m  = gm & 63;
    const float* eps = (g == 0) ? epsA : (g == 1) ? epsB : epsC;
    float4 e = ((const float4*)(eps + ((size_t)m * 512 + n) * D))[ci];
    float4 u = ((const float4*)(mu    + ((size_t)(g * 512 + n)) * D))[ci];
    float4 s = ((const float4*)(sigma + ((size_t)(g * 512 + n)) * D))[ci];
    unsigned short b0 = f2bf(fmaf(s.x, e.x, u.x));
    unsigned short b1 = f2bf(fmaf(s.y, e.y, u.y));
    unsigned short b2 = f2bf(fmaf(s.z, e.z, u.z));
    unsigned short b3 = f2bf(fmaf(s.w, e.w, u.w));
    float f0 = bf2f(b0), f1 = bf2f(b1), f2 = bf2f(b2), f3 = bf2f(b3);
    float ss = f0 * f0 + f1 * f1 + f2 * f2 + f3 * f3;
    uint2 packed;
    packed.x = (unsigned)b0 | ((unsigned)b1 << 16);
    packed.y = (unsigned)b2 | ((unsigned)b3 << 16);
    ((uint2*)(Xb + (size_t)row * D))[ci] = packed;
    #pragma unroll
    for (int o = 16; o > 0; o >>= 1) ss += __shfl_down(ss, o, 32);
    if (ci == 0) sumsq[row] = ss;
}

// One block = one 128x128 tile. K=128 split into two 32 KB stage+compute
// phases through ONE half-K LDS buffer -> 33.8 KB -> 4 blocks/CU (the HW cap
// for a 64-reg accumulator: waves/CU steps at vgpr={64,128,256}, so >64 regs
// means 16 waves/CU max -- do NOT bound waves/SIMD above 4, it spills; R10
// proved this at 150 MB scratch WRITE). Staging = global_load_lds DMA from
// the XCD-local L2 (slice swizzle). 3 resident peer blocks cover each drain.
__global__ __launch_bounds__(256, 4) void dist_kernel(
    const unsigned short* __restrict__ Xb, const float* __restrict__ sumsq,
    float* __restrict__ pslots)
{
    const int bx   = blockIdx.x;          // 0..3071
    const int xcd  = bx & 7;
    const int k    = bx >> 3;             // 0..383
    const int j    = k >> 4;              // 0..23
    const int tile = k & 15;
    const int s    = xcd + 8 * j;         // slice 0..191 = dist*64 + m
    const int dist = s >> 6;
    const int m    = s & 63;
    const int tn   = tile >> 2, tk = tile & 3;

    // dist 0: AC (x=A=0, y=C=2); dist 1: BA (x=B=1, y=A=0); dist 2: BC (x=B=1, y=C=2)
    const int gx = (dist == 0) ? 0 : 1;
    const int gy = (dist == 1) ? 0 : 2;

    const char* Xa = (const char*)(Xb + (((size_t)(gx * 64 + m)) * 512 + tn * 128) * D);
    const char* Xc = (const char*)(Xb + (((size_t)(gy * 64 + m)) * 512 + tk * 128) * D);
    const float* ssx = sumsq + ((size_t)(gx * 64 + m)) * 512 + tn * 128;
    const float* ssy = sumsq + ((size_t)(gy * 64 + m)) * 512 + tk * 128;

    __shared__ unsigned short As[128 * 64];   // 16 KB, half-K A
    __shared__ unsigned short Bs[128 * 64];   // 16 KB, half-K B
    __shared__ float ss_s[256];               // x2 rows | y2 rows

    const int t = threadIdx.x;
    const int wave = t >> 6, lane = t & 63;
    const int wr = (wave >> 1) * 64;      // wave's 64x64 quadrant
    const int wc = (wave & 1) * 64;
    const int l15 = lane & 15, quad = lane >> 4;

    // staging lane map: 8 rows x 8 granules per instr (1 KB).
    // LDS granule-in-row sg = lane&7; global granule g = sg ^ (row&7).
    const int dr8 = lane >> 3, g8 = lane & 7;
    const int voff = dr8 * 256 + ((g8 ^ dr8) * 16);

    f32x4 acc[4][4] = {};

    // ---- phase 0: stage K-cols [0,64) + ss rows ----
    #pragma unroll
    for (int i = 0; i < 4; i++) {
        const int r0 = wave * 32 + i * 8;
        gl2lds16(Xa + r0 * 256 + voff, &As[r0 * 64]);
        gl2lds16(Xc + r0 * 256 + voff, &Bs[r0 * 64]);
    }
    {
        const float* sp = (wave & 2) ? ssy : ssx;
        gl2lds4(sp + (wave & 1) * 64 + lane, &ss_s[wave * 64]);
    }
    __syncthreads();

    #pragma unroll
    for (int ks = 0; ks < 2; ks++) {
        const int base = ((ks * 4 + quad) ^ (l15 & 7)) * 8;
        bf16x8 a[4], b[4];
        #pragma unroll
        for (int fr = 0; fr < 4; fr++)
            a[fr] = *(bf16x8*)&As[(wr + fr * 16 + l15) * 64 + base];
        #pragma unroll
        for (int fc = 0; fc < 4; fc++)
            b[fc] = *(bf16x8*)&Bs[(wc + fc * 16 + l15) * 64 + base];
        #pragma unroll
        for (int fr = 0; fr < 4; fr++)
            #pragma unroll
            for (int fc = 0; fc < 4; fc++)
                acc[fr][fc] = __builtin_amdgcn_mfma_f32_16x16x32_bf16(
                    a[fr], b[fc], acc[fr][fc], 0, 0, 0);
    }
    __syncthreads();

    // ---- phase 1: stage K-cols [64,128) into the same buffer ----
    #pragma unroll
    for (int i = 0; i < 4; i++) {
        const int r0 = wave * 32 + i * 8;
        gl2lds16(Xa + r0 * 256 + 128 + voff, &As[r0 * 64]);
        gl2lds16(Xc + r0 * 256 + 128 + voff, &Bs[r0 * 64]);
    }
    __syncthreads();

    #pragma unroll
    for (int ks = 0; ks < 2; ks++) {
        const int base = ((ks * 4 + quad) ^ (l15 & 7)) * 8;
        bf16x8 a[4], b[4];
        #pragma unroll
        for (int fr = 0; fr < 4; fr++)
            a[fr] = *(bf16x8*)&As[(wr + fr * 16 + l15) * 64 + base];
        #pragma unroll
        for (int fc = 0; fc < 4; fc++)
            b[fc] = *(bf16x8*)&Bs[(wc + fc * 16 + l15) * 64 + base];
        #pragma unroll
        for (int fr = 0; fr < 4; fr++)
            #pragma unroll
            for (int fc = 0; fc < 4; fc++)
                acc[fr][fc] = __builtin_amdgcn_mfma_f32_16x16x32_bf16(
                    a[fr], b[fc], acc[fr][fc], 0, 0, 0);
    }

    // ---- epilogue: d2 = x2 + y2 - 2*dot; C layout: col=lane&15, row=quad*4+i
    float lsum = 0.f;
    #pragma unroll
    for (int fc = 0; fc < 4; fc++) {
        float y2 = ss_s[128 + wc + fc * 16 + l15];
        #pragma unroll
        for (int fr = 0; fr < 4; fr++) {
            #pragma unroll
            for (int i = 0; i < 4; i++) {
                float x2 = ss_s[wr + fr * 16 + quad * 4 + i];
                float d2 = fmaxf(fmaf(-2.f, acc[fr][fc][i], x2 + y2), 1e-12f);
                if (dist == 0) {
                    lsum += d2;                               // mean(dAC^2)
                } else if (d2 < 4.f) {                        // relu(M - d), M=2
                    float td = 2.f - sqrtf(d2);
                    lsum += td * td;
                }
            }
        }
    }

    #pragma unroll
    for (int o = 32; o > 0; o >>= 1) lsum += __shfl_down(lsum, o, 64);
    __syncthreads();                      // ss_s reads done; safe to reuse
    float* red = ss_s;
    if (lane == 0) red[wave] = lsum;
    __syncthreads();
    if (t == 0)
        pslots[bx] = red[0] + red[1] + red[2] + red[3];   // plain store, no atomic
}

// Final reduction: 1 block, 256 threads, 12 floats each -> out[0].
__global__ __launch_bounds__(256) void reduce_kernel(
    const float* __restrict__ pslots, float* __restrict__ out)
{
    const int t = threadIdx.x;
    float s = 0.f;
    #pragma unroll
    for (int i = 0; i < 3; i++) {
        float4 v = ((const float4*)pslots)[t + i * 256];
        s += v.x + v.y + v.z + v.w;
    }
    #pragma unroll
    for (int o = 32; o > 0; o >>= 1) s += __shfl_down(s, o, 64);
    __shared__ float red[4];
    const int wave = t >> 6, lane = t & 63;
    if (lane == 0) red[wave] = s;
    __syncthreads();
    if (t == 0) out[0] = (red[0] + red[1] + red[2] + red[3]) * INV_COUNT;
}

extern "C" void kernel_launch(void* const* d_in, const int* in_sizes, int n_in,
                              void* d_out, int out_size, void* d_ws, size_t ws_size,
                              hipStream_t stream) {
    const float* mu    = (const float*)d_in[0];
    const float* sigma = (const float*)d_in[1];
    const float* epsA  = (const float*)d_in[2];
    const float* epsB  = (const float*)d_in[3];
    const float* epsC  = (const float*)d_in[4];
    float* out = (float*)d_out;

    unsigned short* Xb = (unsigned short*)d_ws;              // 25.17 MB bf16
    float* sumsq  = (float*)((char*)d_ws + X_ELEMS * sizeof(unsigned short)); // 0.39 MB
    float* pslots = sumsq + NROW;                            // 12 KB partials

    prep_kernel<<<NROW / 8, 256, 0, stream>>>(mu, sigma, epsA, epsB, epsC, Xb, sumsq);

    dist_kernel<<<NBLK, 256, 0, stream>>>(Xb, sumsq, pslots);

    reduce_kernel<<<1, 256, 0, stream>>>(pslots, out);
}